// Round 8
// baseline (7067.315 us; speedup 1.0000x reference)
//
#include <hip/hip_runtime.h>
#include <cstdint>

// Problem dims (fixed by reference): B=4096, I=H=1024, K=I+H=2048, N=4H=4096
#define KTOT  2048
#define NTOT  4096

typedef __attribute__((ext_vector_type(4))) float  f32x4;
typedef __attribute__((ext_vector_type(8))) __bf16 bf16x8;
typedef __attribute__((ext_vector_type(8))) unsigned short u16x8;
typedef __attribute__((ext_vector_type(4))) unsigned short u16x4;

__device__ __forceinline__ unsigned short f2bf(float f) {
  uint32_t u = __float_as_uint(f);
  u += 0x7fffu + ((u >> 16) & 1u);   // RNE
  return (unsigned short)(u >> 16);
}
__device__ __forceinline__ float bf2f(unsigned short b) {
  return __uint_as_float(((uint32_t)b) << 16);
}

// ---------------------------------------------------------------------------
// Kernel 1: fused concat/cast (r6/r7-verified)
// ---------------------------------------------------------------------------
__global__ __launch_bounds__(256) void concat2_kernel(
    const float* __restrict__ x,   const float* __restrict__ hx,
    const float* __restrict__ wih, const float* __restrict__ whh,
    unsigned short* __restrict__ Abf, unsigned short* __restrict__ Bbf) {
  int64_t e = ((int64_t)blockIdx.x * 256 + threadIdx.x) * 8;
  const bool second = e >= (int64_t)4096 * 2048;
  if (second) e -= (int64_t)4096 * 2048;
  const float* s0 = second ? wih : x;
  const float* s1 = second ? whh : hx;
  unsigned short* dst = second ? Bbf : Abf;
  int m = (int)(e >> 11);
  int k = (int)(e & 2047);
  const float* src = (k < 1024) ? (s0 + (int64_t)m * 1024 + k)
                                : (s1 + (int64_t)m * 1024 + (k - 1024));
  f32x4 f0 = *(const f32x4*)(src);
  f32x4 f1 = *(const f32x4*)(src + 4);
  u16x8 v;
  v[0] = f2bf(f0[0]); v[1] = f2bf(f0[1]); v[2] = f2bf(f0[2]); v[3] = f2bf(f0[3]);
  v[4] = f2bf(f1[0]); v[5] = f2bf(f1[1]); v[6] = f2bf(f1[2]); v[7] = f2bf(f1[3]);
  *(u16x8*)(dst + e) = v;
}

// ---------------------------------------------------------------------------
// Kernel 2 (PRODUCER, r5-verified: 859 TF, 0 bank conflicts)
// ---------------------------------------------------------------------------
__device__ __forceinline__ void gload_lds16(const void* g, void* lds_p) {
  auto gp = reinterpret_cast<const __attribute__((address_space(1))) uint32_t*>(
      reinterpret_cast<uintptr_t>(g));
  auto lp = reinterpret_cast<__attribute__((address_space(3))) uint32_t*>(
      reinterpret_cast<uintptr_t>(lds_p));
  __builtin_amdgcn_global_load_lds(gp, lp, 16, 0, 0);
}

__global__ __launch_bounds__(256) void gemm_bt_kernel(
    const unsigned short* __restrict__ A,
    const unsigned short* __restrict__ B,
    unsigned short* __restrict__ C) {
  __shared__ unsigned short As[128 * 64];
  __shared__ unsigned short Bs[128 * 64];

  const int tid  = threadIdx.x;
  const int lane = tid & 63;
  const int wid  = tid >> 6;
  const int bm = blockIdx.y, bn = blockIdx.x;

  const int r0 = tid >> 3, c0 = tid & 7;
  const int kcol = ((c0 ^ (r0 & 7)) * 8);
  const unsigned short* gA[4];
  const unsigned short* gB[4];
#pragma unroll
  for (int s = 0; s < 4; ++s) {
    gA[s] = A + ((int64_t)(bm * 128 + s * 32 + r0)) * KTOT + kcol;
    gB[s] = B + ((int64_t)(bn * 128 + s * 32 + r0)) * KTOT + kcol;
  }

  const int wr = wid >> 1, wc = wid & 1;
  const int fr = lane & 15, fq = lane >> 4;

  const int jsw0 = ((fq) ^ (fr & 7)) * 8;
  const int jsw1 = ((4 + fq) ^ (fr & 7)) * 8;
  const unsigned short* aB0 = As + (wr * 64 + fr) * 64 + jsw0;
  const unsigned short* aB1 = As + (wr * 64 + fr) * 64 + jsw1;
  const unsigned short* bB0 = Bs + (wc * 64 + fr) * 64 + jsw0;
  const unsigned short* bB1 = Bs + (wc * 64 + fr) * 64 + jsw1;

  f32x4 acc[4][4] = {};

  for (int kt = 0; kt < KTOT / 64; ++kt) {
#pragma unroll
    for (int s = 0; s < 4; ++s) {
      gload_lds16(gA[s], As + s * 2048 + wid * 512);
      gload_lds16(gB[s], Bs + s * 2048 + wid * 512);
      gA[s] += 64; gB[s] += 64;
    }
    __syncthreads();

    bf16x8 af[4][2], bfr[4][2];
#pragma unroll
    for (int i = 0; i < 4; ++i) {
      af[i][0]  = *(const bf16x8*)(aB0 + i * 1024);
      af[i][1]  = *(const bf16x8*)(aB1 + i * 1024);
      bfr[i][0] = *(const bf16x8*)(bB0 + i * 1024);
      bfr[i][1] = *(const bf16x8*)(bB1 + i * 1024);
    }

#pragma unroll
    for (int ks = 0; ks < 2; ++ks)
#pragma unroll
      for (int i = 0; i < 4; ++i)
#pragma unroll
        for (int j = 0; j < 4; ++j)
          acc[i][j] = __builtin_amdgcn_mfma_f32_16x16x32_bf16(
              af[i][ks], bfr[j][ks], acc[i][j], 0, 0, 0);
    __syncthreads();
  }

#pragma unroll
  for (int i = 0; i < 4; ++i)
#pragma unroll
    for (int j = 0; j < 4; ++j)
#pragma unroll
      for (int r = 0; r < 4; ++r) {
        int m = bm * 128 + wr * 64 + i * 16 + fq * 4 + r;
        int n = bn * 128 + wc * 64 + j * 16 + fr;
        C[(int64_t)m * NTOT + n] = f2bf(acc[i][j][r]);
      }
}

// ---------------------------------------------------------------------------
// Shared 256x256 addressing machinery (shadow kernels)
// ---------------------------------------------------------------------------
#define STAGE(gp, ldsoff, goff)                                               \
  __builtin_amdgcn_global_load_lds(                                           \
      reinterpret_cast<const __attribute__((address_space(1))) uint32_t*>(    \
          reinterpret_cast<uintptr_t>(gp)),                                   \
      reinterpret_cast<__attribute__((address_space(3))) uint32_t*>(          \
          reinterpret_cast<uintptr_t>(lds + (ldsoff))), 16, (goff), 0)

#define CFENCE() asm volatile("" ::: "memory")
#define SCHED0() __builtin_amdgcn_sched_barrier(0)
#define BARF()   do { CFENCE(); __builtin_amdgcn_s_barrier(); CFENCE(); } while (0)
#define LGKM0()  do { asm volatile("s_waitcnt lgkmcnt(0)" ::: "memory"); SCHED0(); } while (0)
#define VM6()    do { asm volatile("s_waitcnt vmcnt(6)" ::: "memory"); SCHED0(); } while (0)
#define VM0()    do { asm volatile("s_waitcnt vmcnt(0)" ::: "memory"); SCHED0(); } while (0)

#define A_DST(slot, kh, h) ((slot)*16384 + (kh)*8192 + (h)*4096 + w*512)
#define B_DST(slot, kh, h) (32768 + A_DST(slot, kh, h))

#define LOAD_A(slotPtr, mh)                                                   \
  _Pragma("unroll") for (int mf = 0; mf < 4; ++mf)                            \
  _Pragma("unroll") for (int ks = 0; ks < 2; ++ks)                            \
    a[mf][ks] = *(const bf16x8*)((slotPtr) + ks*8192 + (mh)*4096 + mf*512);

#define LOAD_B(slotPtr, nh, breg)                                             \
  _Pragma("unroll") for (int nf = 0; nf < 2; ++nf)                            \
  _Pragma("unroll") for (int ks = 0; ks < 2; ++ks)                            \
    breg[nf][ks] = *(const bf16x8*)((slotPtr) + ks*8192 + (nh)*4096 + nf*512);

#define MFMA_Q(mo, no, breg)                                                  \
  __builtin_amdgcn_s_setprio(1);                                              \
  _Pragma("unroll") for (int ks = 0; ks < 2; ++ks)                            \
  _Pragma("unroll") for (int mf = 0; mf < 4; ++mf)                            \
  _Pragma("unroll") for (int nf = 0; nf < 2; ++nf)                            \
    acc[(mo)+mf][(no)+nf] = __builtin_amdgcn_mfma_f32_16x16x32_bf16(          \
        a[mf][ks], breg[nf][ks], acc[(mo)+mf][(no)+nf], 0, 0, 0);             \
  __builtin_amdgcn_s_setprio(0);

#define G256_SETUP                                                            \
  const int tid = threadIdx.x;                                                \
  const int w = tid >> 6;                                                     \
  const int l = tid & 63;                                                     \
  const int fr = l & 15, fq = l >> 4;                                         \
  const int wr = w >> 2, wc = w & 3;                                          \
  const int wg = blockIdx.x;                                                  \
  const int sw = (wg & 7) * 32 + (wg >> 3);                                   \
  const int bm = sw >> 4, bn = sw & 15;                                       \
  const int axk = (fq * 8) ^ ((fr & 8) << 1);                                 \
  const unsigned short* aRd0 = lds + (wr * 2048 + fr * 32 + axk);             \
  const unsigned short* aRd1 = aRd0 + 16384;                                  \
  const unsigned short* bRd0 = lds + 32768 + (wc * 1024 + fr * 32 + axk);     \
  const unsigned short* bRd1 = bRd0 + 16384;                                  \
  const int rsub = l >> 2;                                                    \
  const int kcol = ((l & 3) * 8) ^ ((l & 32) ? 16 : 0);                       \
  const int mlog0 = (w >> 2) * 128 + (w & 3) * 16 + rsub;                     \
  const int mlog1 = mlog0 + 64;                                               \
  const int nlog0 = (w >> 1) * 64 + (w & 1) * 16 + rsub;                      \
  const int nlog1 = nlog0 + 32;                                               \
  const unsigned short* pA0 = A + (int64_t)(bm * 256 + mlog0) * KTOT + kcol;  \
  const unsigned short* pA1 = A + (int64_t)(bm * 256 + mlog1) * KTOT + kcol;  \
  const unsigned short* pB0 = B + (int64_t)(bn * 256 + nlog0) * KTOT + kcol;  \
  const unsigned short* pB1 = B + (int64_t)(bn * 256 + nlog1) * KTOT + kcol;

#define G256_EPILOGUE                                                         \
  _Pragma("unroll") for (int mi = 0; mi < 8; ++mi)                            \
  _Pragma("unroll") for (int nj = 0; nj < 4; ++nj)                            \
  _Pragma("unroll") for (int r = 0; r < 4; ++r) {                             \
    int m = bm * 256 + wr * 128 + mi * 16 + fq * 4 + r;                       \
    int n = bn * 256 + wc * 64 + nj * 16 + fr;                                \
    C[(int64_t)m * NTOT + n] = f2bf(acc[mi][nj][r]);                          \
  }

// ---------------------------------------------------------------------------
// SHADOW A: conservative 256x256 — IDENTICAL addressing, zero pipelining.
// Every kt: stage 8 -> vmcnt(0) -> barrier -> ds_read -> lgkmcnt(0) -> MFMA
// -> barrier.  Correct-by-construction sync; tests addressing only.
// ---------------------------------------------------------------------------
__global__ __launch_bounds__(512) void gemm256c_kernel(
    const unsigned short* __restrict__ A,
    const unsigned short* __restrict__ B,
    unsigned short* __restrict__ C) {
  __shared__ unsigned short lds[65536];
  G256_SETUP

  f32x4 acc[8][4] = {};
  bf16x8 a[4][2], b0[2][2], b1[2][2];

  for (int kt = 0; kt < KTOT / 64; ++kt) {
    STAGE(pA0, A_DST(0,0,0), 0); STAGE(pA0, A_DST(0,1,0), 64);
    STAGE(pA1, A_DST(0,0,1), 0); STAGE(pA1, A_DST(0,1,1), 64);
    STAGE(pB0, B_DST(0,0,0), 0); STAGE(pB0, B_DST(0,1,0), 64);
    STAGE(pB1, B_DST(0,0,1), 0); STAGE(pB1, B_DST(0,1,1), 64);
    pA0 += 64; pA1 += 64; pB0 += 64; pB1 += 64;
    VM0(); BARF();                       // all DMA landed, all waves synced

    LOAD_A(aRd0, 0); LOAD_B(bRd0, 0, b0); LOAD_B(bRd0, 1, b1);
    LGKM0();
    MFMA_Q(0, 0, b0); MFMA_Q(0, 2, b1);
    LOAD_A(aRd0, 1);
    LGKM0();
    MFMA_Q(4, 0, b0); MFMA_Q(4, 2, b1);
    BARF();                              // all reads done before next stage
  }
  G256_EPILOGUE
}

// ---------------------------------------------------------------------------
// SHADOW B: the r7 8-phase pipelined kernel, UNCHANGED (known-mismatching).
// ---------------------------------------------------------------------------
__global__ __launch_bounds__(512) void gemm256_kernel(
    const unsigned short* __restrict__ A,
    const unsigned short* __restrict__ B,
    unsigned short* __restrict__ C) {
  __shared__ unsigned short lds[65536];
  G256_SETUP

  STAGE(pA0, A_DST(0,0,0), 0);   STAGE(pA0, A_DST(0,1,0), 64);
  STAGE(pA1, A_DST(0,0,1), 0);   STAGE(pA1, A_DST(0,1,1), 64);
  STAGE(pB0, B_DST(0,0,0), 0);   STAGE(pB0, B_DST(0,1,0), 64);
  STAGE(pB1, B_DST(0,0,1), 0);   STAGE(pB1, B_DST(0,1,1), 64);
  CFENCE();
  STAGE(pA0, A_DST(1,0,0), 128); STAGE(pA0, A_DST(1,1,0), 192);
  STAGE(pB0, B_DST(1,0,0), 128); STAGE(pB0, B_DST(1,1,0), 192);
  STAGE(pA1, A_DST(1,0,1), 128); STAGE(pA1, A_DST(1,1,1), 192);
  CFENCE();
  VM6();
  BARF();

  f32x4 acc[8][4] = {};
  bf16x8 a[4][2], b0[2][2], b1[2][2];

  for (int it = 0; it < KTOT / 128; ++it) {
    pA0 += 128; pA1 += 128; pB0 += 128; pB1 += 128;
    const unsigned short* pB1m = pB1 - 64;

    LOAD_A(aRd0, 0); LOAD_B(bRd0, 0, b0);
    STAGE(pB1m, B_DST(1,0,1), 0); STAGE(pB1m, B_DST(1,1,1), 64);
    if (it == KTOT / 128 - 1) {
      pA0 -= KTOT; pA1 -= KTOT; pB0 -= KTOT; pB1 -= KTOT;
    }
    BARF(); LGKM0();
    MFMA_Q(0, 0, b0); BARF();

    LOAD_B(bRd0, 1, b1);
    STAGE(pA0, A_DST(0,0,0), 0); STAGE(pA0, A_DST(0,1,0), 64);
    BARF(); LGKM0();
    MFMA_Q(0, 2, b1); BARF();

    LOAD_A(aRd0, 1);
    STAGE(pB0, B_DST(0,0,0), 0); STAGE(pB0, B_DST(0,1,0), 64);
    BARF(); LGKM0();
    MFMA_Q(4, 0, b0); BARF();

    STAGE(pA1, A_DST(0,0,1), 0); STAGE(pA1, A_DST(0,1,1), 64);
    VM6();
    BARF(); LGKM0();
    MFMA_Q(4, 2, b1); BARF();

    LOAD_A(aRd1, 0); LOAD_B(bRd1, 0, b0);
    STAGE(pB1, B_DST(0,0,1), 0); STAGE(pB1, B_DST(0,1,1), 64);
    BARF(); LGKM0();
    MFMA_Q(0, 0, b0); BARF();

    LOAD_B(bRd1, 1, b1);
    STAGE(pA0, A_DST(1,0,0), 128); STAGE(pA0, A_DST(1,1,0), 192);
    BARF(); LGKM0();
    MFMA_Q(0, 2, b1); BARF();

    LOAD_A(aRd1, 1);
    STAGE(pB0, B_DST(1,0,0), 128); STAGE(pB0, B_DST(1,1,0), 192);
    BARF(); LGKM0();
    MFMA_Q(4, 0, b0); BARF();

    STAGE(pA1, A_DST(1,0,1), 128); STAGE(pA1, A_DST(1,1,1), 192);
    VM6();
    BARF(); LGKM0();
    MFMA_Q(4, 2, b1); BARF();
  }

  VM0();
  G256_EPILOGUE
}

// ---------------------------------------------------------------------------
// diff kernels: duration encodes verdict (clean ~12 us; spin ~ cnt-scaled).
// ---------------------------------------------------------------------------
__device__ __forceinline__ void diff_body(const unsigned short* g1,
                                          const unsigned short* g2) {
  int64_t base = ((int64_t)blockIdx.x * 256 + threadIdx.x) * 16;
  int cnt = 0;
#pragma unroll
  for (int i = 0; i < 16; i += 8) {
    u16x8 va = *(const u16x8*)(g1 + base + i);
    u16x8 vb = *(const u16x8*)(g2 + base + i);
#pragma unroll
    for (int j = 0; j < 8; ++j) {
      float d = bf2f(va[j]) - bf2f(vb[j]);
      if (!(__builtin_fabsf(d) <= 0.25f)) cnt++;
    }
  }
  if (cnt > 0)
    for (int i = 0; i < cnt * 2500; ++i) asm volatile("s_nop 7");
}

__global__ __launch_bounds__(256) void diff_consv_kernel(
    const unsigned short* __restrict__ g1, const unsigned short* __restrict__ g2) {
  diff_body(g1, g2);
}
__global__ __launch_bounds__(256) void diff_8ph_kernel(
    const unsigned short* __restrict__ g1, const unsigned short* __restrict__ g2) {
  diff_body(g1, g2);
}

// ---------------------------------------------------------------------------
// Kernel 3: wave-per-gate LayerNorm + LSTM pointwise (r6/r7-verified)
// ---------------------------------------------------------------------------
__device__ __forceinline__ float2 block_meanvar(float s, float ss, float* sbuf,
                                                int lane, int wid) {
#pragma unroll
  for (int off = 32; off > 0; off >>= 1) {
    s  += __shfl_down(s, off);
    ss += __shfl_down(ss, off);
  }
  if (lane == 0) { sbuf[wid] = s; sbuf[4 + wid] = ss; }
  __syncthreads();
  if (threadIdx.x == 0) {
    float S  = sbuf[0] + sbuf[1] + sbuf[2] + sbuf[3];
    float SS = sbuf[4] + sbuf[5] + sbuf[6] + sbuf[7];
    float mean = S * (1.0f / 1024.0f);
    float var  = SS * (1.0f / 1024.0f) - mean * mean;
    var = fmaxf(var, 0.0f);
    float vf = (var < 1e-12f) ? 0.01f : 0.0f;
    sbuf[8] = mean;
    sbuf[9] = 1.0f / sqrtf(var + 1e-12f + vf);
  }
  __syncthreads();
  return make_float2(sbuf[8], sbuf[9]);
}

__device__ __forceinline__ float sigmoidf_(float x) {
  return 1.0f / (1.0f + expf(-x));
}

__global__ __launch_bounds__(256) void lstm_post2_kernel(
    const unsigned short* __restrict__ gates,
    const float* __restrict__ cx,
    const float* __restrict__ gamma,
    const float* __restrict__ beta,
    float* __restrict__ out) {
  __shared__ float act[4][1024];
  __shared__ float red[10];
  const int b = blockIdx.x;
  const int t = threadIdx.x;
  const int lane = t & 63, g = t >> 6;

  const unsigned short* grow = gates + (int64_t)b * 4096 + (g << 10);
  float v[4][4];
  float s = 0.f, ss = 0.f;
#pragma unroll
  for (int q = 0; q < 4; ++q) {
    u16x4 raw = *(const u16x4*)(grow + q * 256 + lane * 4);
#pragma unroll
    for (int j = 0; j < 4; ++j) {
      float f = bf2f(raw[j]);
      v[q][j] = f; s += f; ss += f * f;
    }
  }
#pragma unroll
  for (int off = 32; off > 0; off >>= 1) {
    s  += __shfl_xor(s, off);
    ss += __shfl_xor(ss, off);
  }
  float mean = s * (1.0f / 1024.0f);
  float var  = fmaxf(ss * (1.0f / 1024.0f) - mean * mean, 0.0f);
  float vf   = (var < 1e-12f) ? 0.01f : 0.0f;
  float rstd = 1.0f / sqrtf(var + 1e-12f + vf);

#pragma unroll
  for (int q = 0; q < 4; ++q) {
    const int idx = q * 256 + lane * 4;
    f32x4 gm = *(const f32x4*)(gamma + (g << 10) + idx);
    f32x4 bt = *(const f32x4*)(beta  + (g << 10) + idx);
    f32x4 aa;
#pragma unroll
    for (int j = 0; j < 4; ++j) {
      float n = (v[q][j] - mean) * rstd * gm[j] + bt[j];
      if (g == 1)      aa[j] = sigmoidf_(n + 1.0f);
      else if (g == 2) aa[j] = tanhf(n);
      else             aa[j] = sigmoidf_(n);
    }
    *(f32x4*)(&act[g][idx]) = aa;
  }
  __syncthreads();

  const int h = t * 4;
  f32x4 ig  = *(const f32x4*)(&act[0][h]);
  f32x4 fg  = *(const f32x4*)(&act[1][h]);
  f32x4 cg  = *(const f32x4*)(&act[2][h]);
  f32x4 og  = *(const f32x4*)(&act[3][h]);
  f32x4 cxv = *(const f32x4*)(cx + ((int64_t)b << 10) + h);

  float cyr[4];
  float s2 = 0.f, ss2 = 0.f;
#pragma unroll
  for (int j = 0; j < 4; ++j) {
    cyr[j] = fg[j] * cxv[j] + ig[j] * cg[j];
    s2 += cyr[j]; ss2 += cyr[j] * cyr[j];
  }
  float2 mv = block_meanvar(s2, ss2, red, lane, g);
  f32x4 gm4 = *(const f32x4*)(gamma + 4096 + h);
  f32x4 bt4 = *(const f32x4*)(beta  + 4096 + h);

  f32x4 hy, cyn;
#pragma unroll
  for (int j = 0; j < 4; ++j) {
    float n = (cyr[j] - mv.x) * mv.y * gm4[j] + bt4[j];
    cyn[j] = n;
    hy[j]  = og[j] * tanhf(n);
  }

  const int64_t base = ((int64_t)b << 10) + h;
  *(f32x4*)(out + base)                    = hy;
  *(f32x4*)(out + (int64_t)4194304 + base) = hy;
  *(f32x4*)(out + (int64_t)8388608 + base) = cyn;
}

// ---------------------------------------------------------------------------
extern "C" void kernel_launch(void* const* d_in, const int* in_sizes, int n_in,
                              void* d_out, int out_size, void* d_ws, size_t ws_size,
                              hipStream_t stream) {
  (void)in_sizes; (void)n_in; (void)out_size;
  const float* x     = (const float*)d_in[0];
  const float* hx    = (const float*)d_in[1];
  const float* cx    = (const float*)d_in[2];
  const float* wih   = (const float*)d_in[3];
  const float* whh   = (const float*)d_in[4];
  const float* gamma = (const float*)d_in[5];
  const float* beta  = (const float*)d_in[6];
  float* out = (float*)d_out;

  unsigned short* Abf   = (unsigned short*)d_ws;            // 16MB
  unsigned short* Bbf   = Abf + (size_t)4096 * 2048;        // 16MB
  unsigned short* gates = Bbf + (size_t)4096 * 2048;        // 32MB

  concat2_kernel<<<8192, 256, 0, stream>>>(x, hx, wih, whh, Abf, Bbf);
  gemm_bt_kernel<<<dim3(32, 32), 256, 0, stream>>>(Abf, Bbf, gates);
  lstm_post2_kernel<<<4096, 256, 0, stream>>>(gates, cx, gamma, beta, out);

  // Shadow bisect (scratch-only, shared gates2 buffer, sequential diffs).
  if (ws_size >= (size_t)100663296) {   // 96 MB
    unsigned short* gates2 = gates + (size_t)4096 * 4096;   // +32MB
    gemm256c_kernel<<<256, 512, 0, stream>>>(Abf, Bbf, gates2);
    diff_consv_kernel<<<4096, 256, 0, stream>>>(gates, gates2);
    gemm256_kernel<<<256, 512, 0, stream>>>(Abf, Bbf, gates2);
    diff_8ph_kernel<<<4096, 256, 0, stream>>>(gates, gates2);
  }
}

// Round 9
// 1710.744 us; speedup vs baseline: 4.1311x; 4.1311x over previous
//
#include <hip/hip_runtime.h>
#include <cstdint>

// Problem dims (fixed by reference): B=4096, I=H=1024, K=I+H=2048, N=4H=4096
#define KTOT  2048
#define NTOT  4096

typedef __attribute__((ext_vector_type(4))) float  f32x4;
typedef __attribute__((ext_vector_type(8))) __bf16 bf16x8;
typedef __attribute__((ext_vector_type(8))) unsigned short u16x8;
typedef __attribute__((ext_vector_type(4))) unsigned short u16x4;

__device__ __forceinline__ unsigned short f2bf(float f) {
  uint32_t u = __float_as_uint(f);
  u += 0x7fffu + ((u >> 16) & 1u);   // RNE
  return (unsigned short)(u >> 16);
}
__device__ __forceinline__ float bf2f(unsigned short b) {
  return __uint_as_float(((uint32_t)b) << 16);
}

// ---------------------------------------------------------------------------
// Kernel 1: fused concat/cast (r6/r7-verified)
// ---------------------------------------------------------------------------
__global__ __launch_bounds__(256) void concat2_kernel(
    const float* __restrict__ x,   const float* __restrict__ hx,
    const float* __restrict__ wih, const float* __restrict__ whh,
    unsigned short* __restrict__ Abf, unsigned short* __restrict__ Bbf) {
  int64_t e = ((int64_t)blockIdx.x * 256 + threadIdx.x) * 8;
  const bool second = e >= (int64_t)4096 * 2048;
  if (second) e -= (int64_t)4096 * 2048;
  const float* s0 = second ? wih : x;
  const float* s1 = second ? whh : hx;
  unsigned short* dst = second ? Bbf : Abf;
  int m = (int)(e >> 11);
  int k = (int)(e & 2047);
  const float* src = (k < 1024) ? (s0 + (int64_t)m * 1024 + k)
                                : (s1 + (int64_t)m * 1024 + (k - 1024));
  f32x4 f0 = *(const f32x4*)(src);
  f32x4 f1 = *(const f32x4*)(src + 4);
  u16x8 v;
  v[0] = f2bf(f0[0]); v[1] = f2bf(f0[1]); v[2] = f2bf(f0[2]); v[3] = f2bf(f0[3]);
  v[4] = f2bf(f1[0]); v[5] = f2bf(f1[1]); v[6] = f2bf(f1[2]); v[7] = f2bf(f1[3]);
  *(u16x8*)(dst + e) = v;
}

// ---------------------------------------------------------------------------
// Kernel 2 (PRODUCER, r5-verified: 859 TF, 0 bank conflicts)
// ---------------------------------------------------------------------------
__device__ __forceinline__ void gload_lds16(const void* g, void* lds_p) {
  auto gp = reinterpret_cast<const __attribute__((address_space(1))) uint32_t*>(
      reinterpret_cast<uintptr_t>(g));
  auto lp = reinterpret_cast<__attribute__((address_space(3))) uint32_t*>(
      reinterpret_cast<uintptr_t>(lds_p));
  __builtin_amdgcn_global_load_lds(gp, lp, 16, 0, 0);
}
__device__ __forceinline__ void gload_lds16_off64(const void* g, void* lds_p) {
  auto gp = reinterpret_cast<const __attribute__((address_space(1))) uint32_t*>(
      reinterpret_cast<uintptr_t>(g));
  auto lp = reinterpret_cast<__attribute__((address_space(3))) uint32_t*>(
      reinterpret_cast<uintptr_t>(lds_p));
  __builtin_amdgcn_global_load_lds(gp, lp, 16, 64, 0);   // +64B GLOBAL offset
}

__global__ __launch_bounds__(256) void gemm_bt_kernel(
    const unsigned short* __restrict__ A,
    const unsigned short* __restrict__ B,
    unsigned short* __restrict__ C) {
  __shared__ unsigned short As[128 * 64];
  __shared__ unsigned short Bs[128 * 64];

  const int tid  = threadIdx.x;
  const int lane = tid & 63;
  const int wid  = tid >> 6;
  const int bm = blockIdx.y, bn = blockIdx.x;

  const int r0 = tid >> 3, c0 = tid & 7;
  const int kcol = ((c0 ^ (r0 & 7)) * 8);
  const unsigned short* gA[4];
  const unsigned short* gB[4];
#pragma unroll
  for (int s = 0; s < 4; ++s) {
    gA[s] = A + ((int64_t)(bm * 128 + s * 32 + r0)) * KTOT + kcol;
    gB[s] = B + ((int64_t)(bn * 128 + s * 32 + r0)) * KTOT + kcol;
  }

  const int wr = wid >> 1, wc = wid & 1;
  const int fr = lane & 15, fq = lane >> 4;

  const int jsw0 = ((fq) ^ (fr & 7)) * 8;
  const int jsw1 = ((4 + fq) ^ (fr & 7)) * 8;
  const unsigned short* aB0 = As + (wr * 64 + fr) * 64 + jsw0;
  const unsigned short* aB1 = As + (wr * 64 + fr) * 64 + jsw1;
  const unsigned short* bB0 = Bs + (wc * 64 + fr) * 64 + jsw0;
  const unsigned short* bB1 = Bs + (wc * 64 + fr) * 64 + jsw1;

  f32x4 acc[4][4] = {};

  for (int kt = 0; kt < KTOT / 64; ++kt) {
#pragma unroll
    for (int s = 0; s < 4; ++s) {
      gload_lds16(gA[s], As + s * 2048 + wid * 512);
      gload_lds16(gB[s], Bs + s * 2048 + wid * 512);
      gA[s] += 64; gB[s] += 64;
    }
    __syncthreads();

    bf16x8 af[4][2], bfr[4][2];
#pragma unroll
    for (int i = 0; i < 4; ++i) {
      af[i][0]  = *(const bf16x8*)(aB0 + i * 1024);
      af[i][1]  = *(const bf16x8*)(aB1 + i * 1024);
      bfr[i][0] = *(const bf16x8*)(bB0 + i * 1024);
      bfr[i][1] = *(const bf16x8*)(bB1 + i * 1024);
    }

#pragma unroll
    for (int ks = 0; ks < 2; ++ks)
#pragma unroll
      for (int i = 0; i < 4; ++i)
#pragma unroll
        for (int j = 0; j < 4; ++j)
          acc[i][j] = __builtin_amdgcn_mfma_f32_16x16x32_bf16(
              af[i][ks], bfr[j][ks], acc[i][j], 0, 0, 0);
    __syncthreads();
  }

#pragma unroll
  for (int i = 0; i < 4; ++i)
#pragma unroll
    for (int j = 0; j < 4; ++j)
#pragma unroll
      for (int r = 0; r < 4; ++r) {
        int m = bm * 128 + wr * 64 + i * 16 + fq * 4 + r;
        int n = bn * 128 + wc * 64 + j * 16 + fr;
        C[(int64_t)m * NTOT + n] = f2bf(acc[i][j][r]);
      }
}

// ---------------------------------------------------------------------------
// SHADOW FAMILY: conservative 256x256, LINEAR layout (r5 semantics, 8 waves).
// Template param selects the single deviation under test:
//   HI_B  : B region at LDS bytes 98304..131072 (tests >=64KiB DMA dest)
//   GOFF64: global pointers pre-offset -64B, goff=+64 (tests goff semantics)
// ---------------------------------------------------------------------------
template <bool HI_B, bool GOFF64>
__device__ __forceinline__ void gemm256_lin_body(
    const unsigned short* __restrict__ A,
    const unsigned short* __restrict__ B,
    unsigned short* __restrict__ C) {
  __shared__ unsigned short lds[65536];   // 128 KiB
  unsigned short* As = lds;                               // [256][64]
  unsigned short* Bs = lds + (HI_B ? 49152 : 16384);      // [256][64]

  const int tid = threadIdx.x;
  const int w = tid >> 6, l = tid & 63;
  const int fr = l & 15, fq = l >> 4;
  const int wr = w >> 2, wc = w & 3;          // 2M x 4N waves, 128x64 each
  const int wg = blockIdx.x;
  const int sw = (wg & 7) * 32 + (wg >> 3);   // XCD swizzle (bijective)
  const int bm = sw >> 4, bn = sw & 15;

  // staging: thread covers LDS row r0 = tid>>3 of each 64-row group
  const int r0 = tid >> 3, c0 = tid & 7;
  const int kcol = ((c0 ^ (r0 & 7)) * 8);
  const int pre = GOFF64 ? 32 : 0;            // shorts; goff=+64B compensates
  const unsigned short* gA[4];
  const unsigned short* gB[4];
#pragma unroll
  for (int s = 0; s < 4; ++s) {
    gA[s] = A + ((int64_t)(bm * 256 + s * 64 + r0)) * KTOT + kcol - pre;
    gB[s] = B + ((int64_t)(bn * 256 + s * 64 + r0)) * KTOT + kcol - pre;
  }

  const int jsw0 = ((fq) ^ (fr & 7)) * 8;
  const int jsw1 = ((4 + fq) ^ (fr & 7)) * 8;
  const unsigned short* aB = As + (wr * 128 + fr) * 64;
  const unsigned short* bB = Bs + (wc * 64 + fr) * 64;

  f32x4 acc[8][4] = {};
  bf16x8 a[4][2], b[4][2];

  for (int kt = 0; kt < KTOT / 64; ++kt) {
#pragma unroll
    for (int s = 0; s < 4; ++s) {
      if (GOFF64) {
        gload_lds16_off64(gA[s], As + s * 4096 + w * 512);
        gload_lds16_off64(gB[s], Bs + s * 4096 + w * 512);
      } else {
        gload_lds16(gA[s], As + s * 4096 + w * 512);
        gload_lds16(gB[s], Bs + s * 4096 + w * 512);
      }
      gA[s] += 64; gB[s] += 64;
    }
    __syncthreads();

#pragma unroll
    for (int nj = 0; nj < 4; ++nj) {
      b[nj][0] = *(const bf16x8*)(bB + nj * 1024 + jsw0);
      b[nj][1] = *(const bf16x8*)(bB + nj * 1024 + jsw1);
    }
#pragma unroll
    for (int mf = 0; mf < 4; ++mf) {
      a[mf][0] = *(const bf16x8*)(aB + mf * 1024 + jsw0);
      a[mf][1] = *(const bf16x8*)(aB + mf * 1024 + jsw1);
    }
#pragma unroll
    for (int ks = 0; ks < 2; ++ks)
#pragma unroll
      for (int mf = 0; mf < 4; ++mf)
#pragma unroll
        for (int nj = 0; nj < 4; ++nj)
          acc[mf][nj] = __builtin_amdgcn_mfma_f32_16x16x32_bf16(
              a[mf][ks], b[nj][ks], acc[mf][nj], 0, 0, 0);
#pragma unroll
    for (int mf = 0; mf < 4; ++mf) {
      a[mf][0] = *(const bf16x8*)(aB + 4096 + mf * 1024 + jsw0);
      a[mf][1] = *(const bf16x8*)(aB + 4096 + mf * 1024 + jsw1);
    }
#pragma unroll
    for (int ks = 0; ks < 2; ++ks)
#pragma unroll
      for (int mf = 0; mf < 4; ++mf)
#pragma unroll
        for (int nj = 0; nj < 4; ++nj)
          acc[4 + mf][nj] = __builtin_amdgcn_mfma_f32_16x16x32_bf16(
              a[mf][ks], b[nj][ks], acc[4 + mf][nj], 0, 0, 0);
    __syncthreads();
  }

#pragma unroll
  for (int mi = 0; mi < 8; ++mi)
#pragma unroll
    for (int nj = 0; nj < 4; ++nj)
#pragma unroll
      for (int r = 0; r < 4; ++r) {
        int m = bm * 256 + wr * 128 + mi * 16 + fq * 4 + r;
        int n = bn * 256 + wc * 64 + nj * 16 + fr;
        C[(int64_t)m * NTOT + n] = f2bf(acc[mi][nj][r]);
      }
}

__global__ __launch_bounds__(512) void gemm256_s1_kernel(
    const unsigned short* __restrict__ A, const unsigned short* __restrict__ B,
    unsigned short* __restrict__ C) { gemm256_lin_body<false, false>(A, B, C); }
__global__ __launch_bounds__(512) void gemm256_s2_kernel(
    const unsigned short* __restrict__ A, const unsigned short* __restrict__ B,
    unsigned short* __restrict__ C) { gemm256_lin_body<true, false>(A, B, C); }
__global__ __launch_bounds__(512) void gemm256_s3_kernel(
    const unsigned short* __restrict__ A, const unsigned short* __restrict__ B,
    unsigned short* __restrict__ C) { gemm256_lin_body<false, true>(A, B, C); }

// ---------------------------------------------------------------------------
// diff kernels: duration encodes verdict (clean ~12 us; spin ~cnt-scaled).
// ---------------------------------------------------------------------------
__device__ __forceinline__ void diff_body(const unsigned short* g1,
                                          const unsigned short* g2) {
  int64_t base = ((int64_t)blockIdx.x * 256 + threadIdx.x) * 16;
  int cnt = 0;
#pragma unroll
  for (int i = 0; i < 16; i += 8) {
    u16x8 va = *(const u16x8*)(g1 + base + i);
    u16x8 vb = *(const u16x8*)(g2 + base + i);
#pragma unroll
    for (int j = 0; j < 8; ++j) {
      float d = bf2f(va[j]) - bf2f(vb[j]);
      if (!(__builtin_fabsf(d) <= 0.25f)) cnt++;
    }
  }
  if (cnt > 0)
    for (int i = 0; i < cnt * 1000; ++i) asm volatile("s_nop 7");
}

__global__ __launch_bounds__(256) void diff_s1_kernel(
    const unsigned short* __restrict__ g1, const unsigned short* __restrict__ g2) {
  diff_body(g1, g2);
}
__global__ __launch_bounds__(256) void diff_s2_kernel(
    const unsigned short* __restrict__ g1, const unsigned short* __restrict__ g2) {
  diff_body(g1, g2);
}
__global__ __launch_bounds__(256) void diff_s3_kernel(
    const unsigned short* __restrict__ g1, const unsigned short* __restrict__ g2) {
  diff_body(g1, g2);
}

// ---------------------------------------------------------------------------
// Kernel 3: wave-per-gate LayerNorm + LSTM pointwise (r6/r7-verified)
// ---------------------------------------------------------------------------
__device__ __forceinline__ float2 block_meanvar(float s, float ss, float* sbuf,
                                                int lane, int wid) {
#pragma unroll
  for (int off = 32; off > 0; off >>= 1) {
    s  += __shfl_down(s, off);
    ss += __shfl_down(ss, off);
  }
  if (lane == 0) { sbuf[wid] = s; sbuf[4 + wid] = ss; }
  __syncthreads();
  if (threadIdx.x == 0) {
    float S  = sbuf[0] + sbuf[1] + sbuf[2] + sbuf[3];
    float SS = sbuf[4] + sbuf[5] + sbuf[6] + sbuf[7];
    float mean = S * (1.0f / 1024.0f);
    float var  = SS * (1.0f / 1024.0f) - mean * mean;
    var = fmaxf(var, 0.0f);
    float vf = (var < 1e-12f) ? 0.01f : 0.0f;
    sbuf[8] = mean;
    sbuf[9] = 1.0f / sqrtf(var + 1e-12f + vf);
  }
  __syncthreads();
  return make_float2(sbuf[8], sbuf[9]);
}

__device__ __forceinline__ float sigmoidf_(float x) {
  return 1.0f / (1.0f + expf(-x));
}

__global__ __launch_bounds__(256) void lstm_post2_kernel(
    const unsigned short* __restrict__ gates,
    const float* __restrict__ cx,
    const float* __restrict__ gamma,
    const float* __restrict__ beta,
    float* __restrict__ out) {
  __shared__ float act[4][1024];
  __shared__ float red[10];
  const int b = blockIdx.x;
  const int t = threadIdx.x;
  const int lane = t & 63, g = t >> 6;

  const unsigned short* grow = gates + (int64_t)b * 4096 + (g << 10);
  float v[4][4];
  float s = 0.f, ss = 0.f;
#pragma unroll
  for (int q = 0; q < 4; ++q) {
    u16x4 raw = *(const u16x4*)(grow + q * 256 + lane * 4);
#pragma unroll
    for (int j = 0; j < 4; ++j) {
      float f = bf2f(raw[j]);
      v[q][j] = f; s += f; ss += f * f;
    }
  }
#pragma unroll
  for (int off = 32; off > 0; off >>= 1) {
    s  += __shfl_xor(s, off);
    ss += __shfl_xor(ss, off);
  }
  float mean = s * (1.0f / 1024.0f);
  float var  = fmaxf(ss * (1.0f / 1024.0f) - mean * mean, 0.0f);
  float vf   = (var < 1e-12f) ? 0.01f : 0.0f;
  float rstd = 1.0f / sqrtf(var + 1e-12f + vf);

#pragma unroll
  for (int q = 0; q < 4; ++q) {
    const int idx = q * 256 + lane * 4;
    f32x4 gm = *(const f32x4*)(gamma + (g << 10) + idx);
    f32x4 bt = *(const f32x4*)(beta  + (g << 10) + idx);
    f32x4 aa;
#pragma unroll
    for (int j = 0; j < 4; ++j) {
      float n = (v[q][j] - mean) * rstd * gm[j] + bt[j];
      if (g == 1)      aa[j] = sigmoidf_(n + 1.0f);
      else if (g == 2) aa[j] = tanhf(n);
      else             aa[j] = sigmoidf_(n);
    }
    *(f32x4*)(&act[g][idx]) = aa;
  }
  __syncthreads();

  const int h = t * 4;
  f32x4 ig  = *(const f32x4*)(&act[0][h]);
  f32x4 fg  = *(const f32x4*)(&act[1][h]);
  f32x4 cg  = *(const f32x4*)(&act[2][h]);
  f32x4 og  = *(const f32x4*)(&act[3][h]);
  f32x4 cxv = *(const f32x4*)(cx + ((int64_t)b << 10) + h);

  float cyr[4];
  float s2 = 0.f, ss2 = 0.f;
#pragma unroll
  for (int j = 0; j < 4; ++j) {
    cyr[j] = fg[j] * cxv[j] + ig[j] * cg[j];
    s2 += cyr[j]; ss2 += cyr[j] * cyr[j];
  }
  float2 mv = block_meanvar(s2, ss2, red, lane, g);
  f32x4 gm4 = *(const f32x4*)(gamma + 4096 + h);
  f32x4 bt4 = *(const f32x4*)(beta  + 4096 + h);

  f32x4 hy, cyn;
#pragma unroll
  for (int j = 0; j < 4; ++j) {
    float n = (cyr[j] - mv.x) * mv.y * gm4[j] + bt4[j];
    cyn[j] = n;
    hy[j]  = og[j] * tanhf(n);
  }

  const int64_t base = ((int64_t)b << 10) + h;
  *(f32x4*)(out + base)                    = hy;
  *(f32x4*)(out + (int64_t)4194304 + base) = hy;
  *(f32x4*)(out + (int64_t)8388608 + base) = cyn;
}

// ---------------------------------------------------------------------------
extern "C" void kernel_launch(void* const* d_in, const int* in_sizes, int n_in,
                              void* d_out, int out_size, void* d_ws, size_t ws_size,
                              hipStream_t stream) {
  (void)in_sizes; (void)n_in; (void)out_size;
  const float* x     = (const float*)d_in[0];
  const float* hx    = (const float*)d_in[1];
  const float* cx    = (const float*)d_in[2];
  const float* wih   = (const float*)d_in[3];
  const float* whh   = (const float*)d_in[4];
  const float* gamma = (const float*)d_in[5];
  const float* beta  = (const float*)d_in[6];
  float* out = (float*)d_out;

  unsigned short* Abf   = (unsigned short*)d_ws;            // 16MB
  unsigned short* Bbf   = Abf + (size_t)4096 * 2048;        // 16MB
  unsigned short* gates = Bbf + (size_t)4096 * 2048;        // 32MB

  concat2_kernel<<<8192, 256, 0, stream>>>(x, hx, wih, whh, Abf, Bbf);
  gemm_bt_kernel<<<dim3(32, 32), 256, 0, stream>>>(Abf, Bbf, gates);
  lstm_post2_kernel<<<4096, 256, 0, stream>>>(gates, cx, gamma, beta, out);

  // Orthogonal shadow bisect (scratch-only, sequential, shared gates2).
  if (ws_size >= (size_t)100663296) {   // 96 MB
    unsigned short* gates2 = gates + (size_t)4096 * 4096;   // +32MB
    gemm256_s1_kernel<<<256, 512, 0, stream>>>(Abf, Bbf, gates2);
    diff_s1_kernel<<<4096, 256, 0, stream>>>(gates, gates2);
    gemm256_s2_kernel<<<256, 512, 0, stream>>>(Abf, Bbf, gates2);
    diff_s2_kernel<<<4096, 256, 0, stream>>>(gates, gates2);
    gemm256_s3_kernel<<<256, 512, 0, stream>>>(Abf, Bbf, gates2);
    diff_s3_kernel<<<4096, 256, 0, stream>>>(gates, gates2);
  }
}

// Round 10
// 168.465 us; speedup vs baseline: 41.9513x; 10.1549x over previous
//
#include <hip/hip_runtime.h>
#include <cstdint>

// Problem dims (fixed by reference): B=4096, I=H=1024, K=I+H=2048, N=4H=4096
#define KTOT  2048
#define NTOT  4096

typedef __attribute__((ext_vector_type(4))) float  f32x4;
typedef __attribute__((ext_vector_type(8))) __bf16 bf16x8;
typedef __attribute__((ext_vector_type(8))) unsigned short u16x8;
typedef __attribute__((ext_vector_type(4))) unsigned short u16x4;

__device__ __forceinline__ unsigned short f2bf(float f) {
  uint32_t u = __float_as_uint(f);
  u += 0x7fffu + ((u >> 16) & 1u);   // RNE
  return (unsigned short)(u >> 16);
}
__device__ __forceinline__ float bf2f(unsigned short b) {
  return __uint_as_float(((uint32_t)b) << 16);
}

// goff MUST be 0: r9 bisect proved non-zero goff corrupts LDS placement.
__device__ __forceinline__ void gload_lds16(const void* g, void* lds_p) {
  auto gp = reinterpret_cast<const __attribute__((address_space(1))) uint32_t*>(
      reinterpret_cast<uintptr_t>(g));
  auto lp = reinterpret_cast<__attribute__((address_space(3))) uint32_t*>(
      reinterpret_cast<uintptr_t>(lds_p));
  __builtin_amdgcn_global_load_lds(gp, lp, 16, 0, 0);
}

// ---------------------------------------------------------------------------
// Kernel 1: fused concat/cast (r6-r9 verified)
// ---------------------------------------------------------------------------
__global__ __launch_bounds__(256) void concat2_kernel(
    const float* __restrict__ x,   const float* __restrict__ hx,
    const float* __restrict__ wih, const float* __restrict__ whh,
    unsigned short* __restrict__ Abf, unsigned short* __restrict__ Bbf) {
  int64_t e = ((int64_t)blockIdx.x * 256 + threadIdx.x) * 8;
  const bool second = e >= (int64_t)4096 * 2048;
  if (second) e -= (int64_t)4096 * 2048;
  const float* s0 = second ? wih : x;
  const float* s1 = second ? whh : hx;
  unsigned short* dst = second ? Bbf : Abf;
  int m = (int)(e >> 11);
  int k = (int)(e & 2047);
  const float* src = (k < 1024) ? (s0 + (int64_t)m * 1024 + k)
                                : (s1 + (int64_t)m * 1024 + (k - 1024));
  f32x4 f0 = *(const f32x4*)(src);
  f32x4 f1 = *(const f32x4*)(src + 4);
  u16x8 v;
  v[0] = f2bf(f0[0]); v[1] = f2bf(f0[1]); v[2] = f2bf(f0[2]); v[3] = f2bf(f0[3]);
  v[4] = f2bf(f1[0]); v[5] = f2bf(f1[1]); v[6] = f2bf(f1[2]); v[7] = f2bf(f1[3]);
  *(u16x8*)(dst + e) = v;
}

// ---------------------------------------------------------------------------
// Kernel 2 (PRODUCTION): 256x256 2-phase-prefetch GEMM, S1-verified addressing
// (r9 diff-clean), compiler-only sync (r1/r5 envelope).  Double-buffered
// 128 KiB LDS; stage(next) issued before compute(cur); __syncthreads drains.
// ---------------------------------------------------------------------------
__global__ __launch_bounds__(512) void gemm256p_kernel(
    const unsigned short* __restrict__ A,
    const unsigned short* __restrict__ B,
    unsigned short* __restrict__ C) {
  __shared__ unsigned short lds[65536];   // 2 slots x (A 16384 + B 16384)

  const int tid = threadIdx.x;
  const int w = tid >> 6, l = tid & 63;
  const int fr = l & 15, fq = l >> 4;
  const int wr = w >> 2, wc = w & 3;          // 2M x 4N waves, 128x64 each
  const int wg = blockIdx.x;
  const int sw = (wg & 7) * 32 + (wg >> 3);   // XCD swizzle (bijective, 256 wgs)
  const int bm = sw >> 4, bn = sw & 15;

  const int r0 = tid >> 3, c0 = tid & 7;
  const int kcol = ((c0 ^ (r0 & 7)) * 8);     // inverse XOR k-swizzle (r5)
  const unsigned short* gA[4];
  const unsigned short* gB[4];
#pragma unroll
  for (int s = 0; s < 4; ++s) {
    gA[s] = A + ((int64_t)(bm * 256 + s * 64 + r0)) * KTOT + kcol;
    gB[s] = B + ((int64_t)(bn * 256 + s * 64 + r0)) * KTOT + kcol;
  }

  const int jsw0 = ((fq) ^ (fr & 7)) * 8;
  const int jsw1 = ((4 + fq) ^ (fr & 7)) * 8;
  const int aOff = (wr * 128 + fr) * 64;              // within A region
  const int bOff = 16384 + (wc * 64 + fr) * 64;       // within slot (B region)

#define STG(slot)                                                             \
  _Pragma("unroll") for (int s = 0; s < 4; ++s) {                             \
    gload_lds16(gA[s], lds + (slot) * 32768 + s * 4096 + w * 512);            \
    gload_lds16(gB[s], lds + (slot) * 32768 + 16384 + s * 4096 + w * 512);    \
    gA[s] += 64; gB[s] += 64;                                                 \
  }

  f32x4 acc[8][4] = {};
  bf16x8 a[4][2], b[4][2];

#define COMPUTE(slot)                                                         \
  {                                                                           \
    const unsigned short* Ab = lds + (slot) * 32768 + aOff;                   \
    const unsigned short* Bb = lds + (slot) * 32768 + bOff;                   \
    _Pragma("unroll") for (int nj = 0; nj < 4; ++nj) {                        \
      b[nj][0] = *(const bf16x8*)(Bb + nj * 1024 + jsw0);                     \
      b[nj][1] = *(const bf16x8*)(Bb + nj * 1024 + jsw1);                     \
    }                                                                         \
    _Pragma("unroll") for (int mf = 0; mf < 4; ++mf) {                        \
      a[mf][0] = *(const bf16x8*)(Ab + mf * 1024 + jsw0);                     \
      a[mf][1] = *(const bf16x8*)(Ab + mf * 1024 + jsw1);                     \
    }                                                                         \
    _Pragma("unroll") for (int ks = 0; ks < 2; ++ks)                          \
    _Pragma("unroll") for (int mf = 0; mf < 4; ++mf)                          \
    _Pragma("unroll") for (int nj = 0; nj < 4; ++nj)                          \
      acc[mf][nj] = __builtin_amdgcn_mfma_f32_16x16x32_bf16(                  \
          a[mf][ks], b[nj][ks], acc[mf][nj], 0, 0, 0);                        \
    _Pragma("unroll") for (int mf = 0; mf < 4; ++mf) {                        \
      a[mf][0] = *(const bf16x8*)(Ab + 4096 + mf * 1024 + jsw0);              \
      a[mf][1] = *(const bf16x8*)(Ab + 4096 + mf * 1024 + jsw1);              \
    }                                                                         \
    _Pragma("unroll") for (int ks = 0; ks < 2; ++ks)                          \
    _Pragma("unroll") for (int mf = 0; mf < 4; ++mf)                          \
    _Pragma("unroll") for (int nj = 0; nj < 4; ++nj)                          \
      acc[4 + mf][nj] = __builtin_amdgcn_mfma_f32_16x16x32_bf16(              \
          a[mf][ks], b[nj][ks], acc[4 + mf][nj], 0, 0, 0);                    \
  }

  STG(0)
  __syncthreads();
  int cur = 0;
  for (int kt = 0; kt < KTOT / 64 - 1; ++kt) {
    STG(cur ^ 1)            // next tile's 8 DMAs fly during compute
    COMPUTE(cur)
    __syncthreads();        // drains vmcnt+lgkm, syncs all waves
    cur ^= 1;
  }
  COMPUTE(cur)

#pragma unroll
  for (int mi = 0; mi < 8; ++mi)
#pragma unroll
    for (int nj = 0; nj < 4; ++nj)
#pragma unroll
      for (int r = 0; r < 4; ++r) {
        int m = bm * 256 + wr * 128 + mi * 16 + fq * 4 + r;
        int n = bn * 256 + wc * 64 + nj * 16 + fr;
        C[(int64_t)m * NTOT + n] = f2bf(acc[mi][nj][r]);
      }
#undef STG
#undef COMPUTE
}

// ---------------------------------------------------------------------------
// SHADOW: full 8-phase counted-vmcnt 256x256 (r7 schedule) with the goff FIX
// (all global offsets folded into pointers; every STAGE uses goff=0).
// ---------------------------------------------------------------------------
#define STAGE0(gp, ldsoff) gload_lds16((gp), lds + (ldsoff))
#define CFENCE() asm volatile("" ::: "memory")
#define SCHED0() __builtin_amdgcn_sched_barrier(0)
#define BARF()   do { CFENCE(); __builtin_amdgcn_s_barrier(); CFENCE(); } while (0)
#define LGKM0()  do { asm volatile("s_waitcnt lgkmcnt(0)" ::: "memory"); SCHED0(); } while (0)
#define VM6()    do { asm volatile("s_waitcnt vmcnt(6)" ::: "memory"); SCHED0(); } while (0)
#define VM0()    do { asm volatile("s_waitcnt vmcnt(0)" ::: "memory"); SCHED0(); } while (0)

#define A_DST(slot, kh, h) ((slot)*16384 + (kh)*8192 + (h)*4096 + w*512)
#define B_DST(slot, kh, h) (32768 + A_DST(slot, kh, h))

#define LOAD_A(slotPtr, mh)                                                   \
  _Pragma("unroll") for (int mf = 0; mf < 4; ++mf)                            \
  _Pragma("unroll") for (int ks = 0; ks < 2; ++ks)                            \
    a[mf][ks] = *(const bf16x8*)((slotPtr) + ks*8192 + (mh)*4096 + mf*512);

#define LOAD_B(slotPtr, nh, breg)                                             \
  _Pragma("unroll") for (int nf = 0; nf < 2; ++nf)                            \
  _Pragma("unroll") for (int ks = 0; ks < 2; ++ks)                            \
    breg[nf][ks] = *(const bf16x8*)((slotPtr) + ks*8192 + (nh)*4096 + nf*512);

#define MFMA_Q(mo, no, breg)                                                  \
  __builtin_amdgcn_s_setprio(1);                                              \
  _Pragma("unroll") for (int ks = 0; ks < 2; ++ks)                            \
  _Pragma("unroll") for (int mf = 0; mf < 4; ++mf)                            \
  _Pragma("unroll") for (int nf = 0; nf < 2; ++nf)                            \
    acc[(mo)+mf][(no)+nf] = __builtin_amdgcn_mfma_f32_16x16x32_bf16(          \
        a[mf][ks], breg[nf][ks], acc[(mo)+mf][(no)+nf], 0, 0, 0);             \
  __builtin_amdgcn_s_setprio(0);

__global__ __launch_bounds__(512) void gemm256f_kernel(
    const unsigned short* __restrict__ A,
    const unsigned short* __restrict__ B,
    unsigned short* __restrict__ C) {
  __shared__ unsigned short lds[65536];

  const int tid = threadIdx.x;
  const int w = tid >> 6, l = tid & 63;
  const int fr = l & 15, fq = l >> 4;
  const int wr = w >> 2, wc = w & 3;
  const int wg = blockIdx.x;
  const int sw = (wg & 7) * 32 + (wg >> 3);
  const int bm = sw >> 4, bn = sw & 15;

  const int axk = (fq * 8) ^ ((fr & 8) << 1);
  const unsigned short* aRd0 = lds + (wr * 2048 + fr * 32 + axk);
  const unsigned short* aRd1 = aRd0 + 16384;
  const unsigned short* bRd0 = lds + 32768 + (wc * 1024 + fr * 32 + axk);
  const unsigned short* bRd1 = bRd0 + 16384;

  const int rsub = l >> 2;
  const int kcol = ((l & 3) * 8) ^ ((l & 32) ? 16 : 0);
  const int mlog0 = (w >> 2) * 128 + (w & 3) * 16 + rsub;
  const int mlog1 = mlog0 + 64;
  const int nlog0 = (w >> 1) * 64 + (w & 1) * 16 + rsub;
  const int nlog1 = nlog0 + 32;
  const unsigned short* pA0 = A + (int64_t)(bm * 256 + mlog0) * KTOT + kcol;
  const unsigned short* pA1 = A + (int64_t)(bm * 256 + mlog1) * KTOT + kcol;
  const unsigned short* pB0 = B + (int64_t)(bn * 256 + nlog0) * KTOT + kcol;
  const unsigned short* pB1 = B + (int64_t)(bn * 256 + nlog1) * KTOT + kcol;

  // prologue: slot0 <- kt0 (8), slot1 <- kt1 partial (6); ALL goff=0
  STAGE0(pA0,      A_DST(0,0,0)); STAGE0(pA0 + 32, A_DST(0,1,0));
  STAGE0(pA1,      A_DST(0,0,1)); STAGE0(pA1 + 32, A_DST(0,1,1));
  STAGE0(pB0,      B_DST(0,0,0)); STAGE0(pB0 + 32, B_DST(0,1,0));
  STAGE0(pB1,      B_DST(0,0,1)); STAGE0(pB1 + 32, B_DST(0,1,1));
  CFENCE();
  STAGE0(pA0 + 64, A_DST(1,0,0)); STAGE0(pA0 + 96, A_DST(1,1,0));
  STAGE0(pB0 + 64, B_DST(1,0,0)); STAGE0(pB0 + 96, B_DST(1,1,0));
  STAGE0(pA1 + 64, A_DST(1,0,1)); STAGE0(pA1 + 96, A_DST(1,1,1));
  CFENCE();
  VM6();
  BARF();

  f32x4 acc[8][4] = {};
  bf16x8 a[4][2], b0[2][2], b1[2][2];

  for (int it = 0; it < KTOT / 128; ++it) {
    pA0 += 128; pA1 += 128; pB0 += 128; pB1 += 128;   // -> kt 2it+2 base

    // P1: Q(0,0) slot0 | stage slot1.B[h1] @ kt 2it+1 (base-64 shorts)
    LOAD_A(aRd0, 0); LOAD_B(bRd0, 0, b0);
    STAGE0(pB1 - 64, B_DST(1,0,1)); STAGE0(pB1 - 32, B_DST(1,1,1));
    if (it == KTOT / 128 - 1) {   // wrap: remaining prefetches re-read kt0/1
      pA0 -= KTOT; pA1 -= KTOT; pB0 -= KTOT; pB1 -= KTOT;
    }
    BARF(); LGKM0();
    MFMA_Q(0, 0, b0); BARF();

    // P2: Q(0,1) slot0 | stage slot0.A[h0] @ kt 2it+2
    LOAD_B(bRd0, 1, b1);
    STAGE0(pA0,      A_DST(0,0,0)); STAGE0(pA0 + 32, A_DST(0,1,0));
    BARF(); LGKM0();
    MFMA_Q(0, 2, b1); BARF();

    // P3: Q(1,0) slot0 | stage slot0.B[h0]
    LOAD_A(aRd0, 1);
    STAGE0(pB0,      B_DST(0,0,0)); STAGE0(pB0 + 32, B_DST(0,1,0));
    BARF(); LGKM0();
    MFMA_Q(4, 0, b0); BARF();

    // P4: Q(1,1) slot0 | stage slot0.A[h1] | counted vmcnt
    STAGE0(pA1,      A_DST(0,0,1)); STAGE0(pA1 + 32, A_DST(0,1,1));
    VM6();
    BARF(); LGKM0();
    MFMA_Q(4, 2, b1); BARF();

    // P5: Q(0,0) slot1 | stage slot0.B[h1]
    LOAD_A(aRd1, 0); LOAD_B(bRd1, 0, b0);
    STAGE0(pB1,      B_DST(0,0,1)); STAGE0(pB1 + 32, B_DST(0,1,1));
    BARF(); LGKM0();
    MFMA_Q(0, 0, b0); BARF();

    // P6: Q(0,1) slot1 | stage slot1.A[h0] @ kt 2it+3
    LOAD_B(bRd1, 1, b1);
    STAGE0(pA0 + 64, A_DST(1,0,0)); STAGE0(pA0 + 96, A_DST(1,1,0));
    BARF(); LGKM0();
    MFMA_Q(0, 2, b1); BARF();

    // P7: Q(1,0) slot1 | stage slot1.B[h0]
    LOAD_A(aRd1, 1);
    STAGE0(pB0 + 64, B_DST(1,0,0)); STAGE0(pB0 + 96, B_DST(1,1,0));
    BARF(); LGKM0();
    MFMA_Q(4, 0, b0); BARF();

    // P8: Q(1,1) slot1 | stage slot1.A[h1] | counted vmcnt
    STAGE0(pA1 + 64, A_DST(1,0,1)); STAGE0(pA1 + 96, A_DST(1,1,1));
    VM6();
    BARF(); LGKM0();
    MFMA_Q(4, 2, b1); BARF();
  }

  VM0();   // drain dummy wrap stages before LDS dealloc

#pragma unroll
  for (int mi = 0; mi < 8; ++mi)
#pragma unroll
    for (int nj = 0; nj < 4; ++nj)
#pragma unroll
      for (int r = 0; r < 4; ++r) {
        int m = bm * 256 + wr * 128 + mi * 16 + fq * 4 + r;
        int n = bn * 256 + wc * 64 + nj * 16 + fr;
        C[(int64_t)m * NTOT + n] = f2bf(acc[mi][nj][r]);
      }
}

// ---------------------------------------------------------------------------
// diff: duration encodes verdict (clean ~12 us; spin ~cnt-scaled).
// ---------------------------------------------------------------------------
__global__ __launch_bounds__(256) void diff_8f_kernel(
    const unsigned short* __restrict__ g1, const unsigned short* __restrict__ g2) {
  int64_t base = ((int64_t)blockIdx.x * 256 + threadIdx.x) * 16;
  int cnt = 0;
#pragma unroll
  for (int i = 0; i < 16; i += 8) {
    u16x8 va = *(const u16x8*)(g1 + base + i);
    u16x8 vb = *(const u16x8*)(g2 + base + i);
#pragma unroll
    for (int j = 0; j < 8; ++j) {
      float d = bf2f(va[j]) - bf2f(vb[j]);
      if (!(__builtin_fabsf(d) <= 0.25f)) cnt++;
    }
  }
  if (cnt > 0)
    for (int i = 0; i < cnt * 1000; ++i) asm volatile("s_nop 7");
}

// ---------------------------------------------------------------------------
// Kernel 3: wave-per-gate LayerNorm + LSTM pointwise (r6-r9 verified)
// ---------------------------------------------------------------------------
__device__ __forceinline__ float2 block_meanvar(float s, float ss, float* sbuf,
                                                int lane, int wid) {
#pragma unroll
  for (int off = 32; off > 0; off >>= 1) {
    s  += __shfl_down(s, off);
    ss += __shfl_down(ss, off);
  }
  if (lane == 0) { sbuf[wid] = s; sbuf[4 + wid] = ss; }
  __syncthreads();
  if (threadIdx.x == 0) {
    float S  = sbuf[0] + sbuf[1] + sbuf[2] + sbuf[3];
    float SS = sbuf[4] + sbuf[5] + sbuf[6] + sbuf[7];
    float mean = S * (1.0f / 1024.0f);
    float var  = SS * (1.0f / 1024.0f) - mean * mean;
    var = fmaxf(var, 0.0f);
    float vf = (var < 1e-12f) ? 0.01f : 0.0f;
    sbuf[8] = mean;
    sbuf[9] = 1.0f / sqrtf(var + 1e-12f + vf);
  }
  __syncthreads();
  return make_float2(sbuf[8], sbuf[9]);
}

__device__ __forceinline__ float sigmoidf_(float x) {
  return 1.0f / (1.0f + expf(-x));
}

__global__ __launch_bounds__(256) void lstm_post2_kernel(
    const unsigned short* __restrict__ gates,
    const float* __restrict__ cx,
    const float* __restrict__ gamma,
    const float* __restrict__ beta,
    float* __restrict__ out) {
  __shared__ float act[4][1024];
  __shared__ float red[10];
  const int b = blockIdx.x;
  const int t = threadIdx.x;
  const int lane = t & 63, g = t >> 6;

  const unsigned short* grow = gates + (int64_t)b * 4096 + (g << 10);
  float v[4][4];
  float s = 0.f, ss = 0.f;
#pragma unroll
  for (int q = 0; q < 4; ++q) {
    u16x4 raw = *(const u16x4*)(grow + q * 256 + lane * 4);
#pragma unroll
    for (int j = 0; j < 4; ++j) {
      float f = bf2f(raw[j]);
      v[q][j] = f; s += f; ss += f * f;
    }
  }
#pragma unroll
  for (int off = 32; off > 0; off >>= 1) {
    s  += __shfl_xor(s, off);
    ss += __shfl_xor(ss, off);
  }
  float mean = s * (1.0f / 1024.0f);
  float var  = fmaxf(ss * (1.0f / 1024.0f) - mean * mean, 0.0f);
  float vf   = (var < 1e-12f) ? 0.01f : 0.0f;
  float rstd = 1.0f / sqrtf(var + 1e-12f + vf);

#pragma unroll
  for (int q = 0; q < 4; ++q) {
    const int idx = q * 256 + lane * 4;
    f32x4 gm = *(const f32x4*)(gamma + (g << 10) + idx);
    f32x4 bt = *(const f32x4*)(beta  + (g << 10) + idx);
    f32x4 aa;
#pragma unroll
    for (int j = 0; j < 4; ++j) {
      float n = (v[q][j] - mean) * rstd * gm[j] + bt[j];
      if (g == 1)      aa[j] = sigmoidf_(n + 1.0f);
      else if (g == 2) aa[j] = tanhf(n);
      else             aa[j] = sigmoidf_(n);
    }
    *(f32x4*)(&act[g][idx]) = aa;
  }
  __syncthreads();

  const int h = t * 4;
  f32x4 ig  = *(const f32x4*)(&act[0][h]);
  f32x4 fg  = *(const f32x4*)(&act[1][h]);
  f32x4 cg  = *(const f32x4*)(&act[2][h]);
  f32x4 og  = *(const f32x4*)(&act[3][h]);
  f32x4 cxv = *(const f32x4*)(cx + ((int64_t)b << 10) + h);

  float cyr[4];
  float s2 = 0.f, ss2 = 0.f;
#pragma unroll
  for (int j = 0; j < 4; ++j) {
    cyr[j] = fg[j] * cxv[j] + ig[j] * cg[j];
    s2 += cyr[j]; ss2 += cyr[j] * cyr[j];
  }
  float2 mv = block_meanvar(s2, ss2, red, lane, g);
  f32x4 gm4 = *(const f32x4*)(gamma + 4096 + h);
  f32x4 bt4 = *(const f32x4*)(beta  + 4096 + h);

  f32x4 hy, cyn;
#pragma unroll
  for (int j = 0; j < 4; ++j) {
    float n = (cyr[j] - mv.x) * mv.y * gm4[j] + bt4[j];
    cyn[j] = n;
    hy[j]  = og[j] * tanhf(n);
  }

  const int64_t base = ((int64_t)b << 10) + h;
  *(f32x4*)(out + base)                    = hy;
  *(f32x4*)(out + (int64_t)4194304 + base) = hy;
  *(f32x4*)(out + (int64_t)8388608 + base) = cyn;
}

// ---------------------------------------------------------------------------
extern "C" void kernel_launch(void* const* d_in, const int* in_sizes, int n_in,
                              void* d_out, int out_size, void* d_ws, size_t ws_size,
                              hipStream_t stream) {
  (void)in_sizes; (void)n_in; (void)out_size;
  const float* x     = (const float*)d_in[0];
  const float* hx    = (const float*)d_in[1];
  const float* cx    = (const float*)d_in[2];
  const float* wih   = (const float*)d_in[3];
  const float* whh   = (const float*)d_in[4];
  const float* gamma = (const float*)d_in[5];
  const float* beta  = (const float*)d_in[6];
  float* out = (float*)d_out;

  unsigned short* Abf   = (unsigned short*)d_ws;            // 16MB
  unsigned short* Bbf   = Abf + (size_t)4096 * 2048;        // 16MB
  unsigned short* gates = Bbf + (size_t)4096 * 2048;        // 32MB

  concat2_kernel<<<8192, 256, 0, stream>>>(x, hx, wih, whh, Abf, Bbf);
  gemm256p_kernel<<<256, 512, 0, stream>>>(Abf, Bbf, gates);
  lstm_post2_kernel<<<4096, 256, 0, stream>>>(gates, cx, gamma, beta, out);

  // Shadow: goff-fixed 8-phase (scratch-only); verdict = diff_8f duration.
  if (ws_size >= (size_t)100663296) {   // 96 MB
    unsigned short* gates2 = gates + (size_t)4096 * 4096;   // +32MB
    gemm256f_kernel<<<256, 512, 0, stream>>>(Abf, Bbf, gates2);
    diff_8f_kernel<<<4096, 256, 0, stream>>>(gates, gates2);
  }
}

// Round 11
// 101.348 us; speedup vs baseline: 69.7330x; 1.6622x over previous
//
#include <hip/hip_runtime.h>
#include <cstdint>

// Problem dims (fixed by reference): B=4096, I=H=1024, K=I+H=2048, N=4H=4096
#define KTOT  2048
#define NTOT  4096

typedef __attribute__((ext_vector_type(4))) float  f32x4;
typedef __attribute__((ext_vector_type(8))) __bf16 bf16x8;
typedef __attribute__((ext_vector_type(8))) unsigned short u16x8;
typedef __attribute__((ext_vector_type(4))) unsigned short u16x4;

__device__ __forceinline__ unsigned short f2bf(float f) {
  uint32_t u = __float_as_uint(f);
  u += 0x7fffu + ((u >> 16) & 1u);   // RNE
  return (unsigned short)(u >> 16);
}
__device__ __forceinline__ float bf2f(unsigned short b) {
  return __uint_as_float(((uint32_t)b) << 16);
}

// NOTE (r9 bisect, HW-verified): goff argument MUST be 0 — non-zero goff
// corrupts LDS placement on gfx950. Fold all offsets into the pointer.
__device__ __forceinline__ void gload_lds16(const void* g, void* lds_p) {
  auto gp = reinterpret_cast<const __attribute__((address_space(1))) uint32_t*>(
      reinterpret_cast<uintptr_t>(g));
  auto lp = reinterpret_cast<__attribute__((address_space(3))) uint32_t*>(
      reinterpret_cast<uintptr_t>(lds_p));
  __builtin_amdgcn_global_load_lds(gp, lp, 16, 0, 0);
}

// ---------------------------------------------------------------------------
// Kernel 1: fused concat/cast: [x|hx] -> Abf[4096][2048] bf16 and
//           [wih|whh] -> Bbf[4096][2048] bf16 (r6-r10 verified)
// ---------------------------------------------------------------------------
__global__ __launch_bounds__(256) void concat2_kernel(
    const float* __restrict__ x,   const float* __restrict__ hx,
    const float* __restrict__ wih, const float* __restrict__ whh,
    unsigned short* __restrict__ Abf, unsigned short* __restrict__ Bbf) {
  int64_t e = ((int64_t)blockIdx.x * 256 + threadIdx.x) * 8;
  const bool second = e >= (int64_t)4096 * 2048;
  if (second) e -= (int64_t)4096 * 2048;
  const float* s0 = second ? wih : x;
  const float* s1 = second ? whh : hx;
  unsigned short* dst = second ? Bbf : Abf;
  int m = (int)(e >> 11);
  int k = (int)(e & 2047);
  const float* src = (k < 1024) ? (s0 + (int64_t)m * 1024 + k)
                                : (s1 + (int64_t)m * 1024 + (k - 1024));
  f32x4 f0 = *(const f32x4*)(src);
  f32x4 f1 = *(const f32x4*)(src + 4);
  u16x8 v;
  v[0] = f2bf(f0[0]); v[1] = f2bf(f0[1]); v[2] = f2bf(f0[2]); v[3] = f2bf(f0[3]);
  v[4] = f2bf(f1[0]); v[5] = f2bf(f1[1]); v[6] = f2bf(f1[2]); v[7] = f2bf(f1[3]);
  *(u16x8*)(dst + e) = v;
}

// ---------------------------------------------------------------------------
// Kernel 2 (PRODUCTION, r10-verified ~59.5 us ≈ 1155 TF, diff-clean vs r5):
// 256x256 2-phase-prefetch GEMM.  8 waves (2Mx4N, 128x64 out each), BK=64,
// double-buffered 128 KiB LDS, r5 XOR k-swizzle (0 bank conflicts), XCD-aware
// block swizzle, goff=0 everywhere, compiler-only sync (__syncthreads).
// Beat the goff-fixed 8-phase counted-vmcnt variant (65.1 us) at K=2048.
// ---------------------------------------------------------------------------
__global__ __launch_bounds__(512) void gemm256p_kernel(
    const unsigned short* __restrict__ A,
    const unsigned short* __restrict__ B,
    unsigned short* __restrict__ C) {
  __shared__ unsigned short lds[65536];   // 2 slots x (A 16384 + B 16384)

  const int tid = threadIdx.x;
  const int w = tid >> 6, l = tid & 63;
  const int fr = l & 15, fq = l >> 4;
  const int wr = w >> 2, wc = w & 3;          // 2M x 4N waves, 128x64 each
  const int wg = blockIdx.x;
  const int sw = (wg & 7) * 32 + (wg >> 3);   // XCD swizzle (bijective, 256 wgs)
  const int bm = sw >> 4, bn = sw & 15;

  const int r0 = tid >> 3, c0 = tid & 7;
  const int kcol = ((c0 ^ (r0 & 7)) * 8);     // inverse XOR k-swizzle (r5)
  const unsigned short* gA[4];
  const unsigned short* gB[4];
#pragma unroll
  for (int s = 0; s < 4; ++s) {
    gA[s] = A + ((int64_t)(bm * 256 + s * 64 + r0)) * KTOT + kcol;
    gB[s] = B + ((int64_t)(bn * 256 + s * 64 + r0)) * KTOT + kcol;
  }

  const int jsw0 = ((fq) ^ (fr & 7)) * 8;
  const int jsw1 = ((4 + fq) ^ (fr & 7)) * 8;
  const int aOff = (wr * 128 + fr) * 64;              // within A region
  const int bOff = 16384 + (wc * 64 + fr) * 64;       // within slot (B region)

#define STG(slot)                                                             \
  _Pragma("unroll") for (int s = 0; s < 4; ++s) {                             \
    gload_lds16(gA[s], lds + (slot) * 32768 + s * 4096 + w * 512);            \
    gload_lds16(gB[s], lds + (slot) * 32768 + 16384 + s * 4096 + w * 512);    \
    gA[s] += 64; gB[s] += 64;                                                 \
  }

  f32x4 acc[8][4] = {};
  bf16x8 a[4][2], b[4][2];

#define COMPUTE(slot)                                                         \
  {                                                                           \
    const unsigned short* Ab = lds + (slot) * 32768 + aOff;                   \
    const unsigned short* Bb = lds + (slot) * 32768 + bOff;                   \
    _Pragma("unroll") for (int nj = 0; nj < 4; ++nj) {                        \
      b[nj][0] = *(const bf16x8*)(Bb + nj * 1024 + jsw0);                     \
      b[nj][1] = *(const bf16x8*)(Bb + nj * 1024 + jsw1);                     \
    }                                                                         \
    _Pragma("unroll") for (int mf = 0; mf < 4; ++mf) {                        \
      a[mf][0] = *(const bf16x8*)(Ab + mf * 1024 + jsw0);                     \
      a[mf][1] = *(const bf16x8*)(Ab + mf * 1024 + jsw1);                     \
    }                                                                         \
    _Pragma("unroll") for (int ks = 0; ks < 2; ++ks)                          \
    _Pragma("unroll") for (int mf = 0; mf < 4; ++mf)                          \
    _Pragma("unroll") for (int nj = 0; nj < 4; ++nj)                          \
      acc[mf][nj] = __builtin_amdgcn_mfma_f32_16x16x32_bf16(                  \
          a[mf][ks], b[nj][ks], acc[mf][nj], 0, 0, 0);                        \
    _Pragma("unroll") for (int mf = 0; mf < 4; ++mf) {                        \
      a[mf][0] = *(const bf16x8*)(Ab + 4096 + mf * 1024 + jsw0);              \
      a[mf][1] = *(const bf16x8*)(Ab + 4096 + mf * 1024 + jsw1);              \
    }                                                                         \
    _Pragma("unroll") for (int ks = 0; ks < 2; ++ks)                          \
    _Pragma("unroll") for (int mf = 0; mf < 4; ++mf)                          \
    _Pragma("unroll") for (int nj = 0; nj < 4; ++nj)                          \
      acc[4 + mf][nj] = __builtin_amdgcn_mfma_f32_16x16x32_bf16(              \
          a[mf][ks], b[nj][ks], acc[4 + mf][nj], 0, 0, 0);                    \
  }

  STG(0)
  __syncthreads();
  int cur = 0;
  for (int kt = 0; kt < KTOT / 64 - 1; ++kt) {
    STG(cur ^ 1)            // next tile's 8 DMAs fly during compute
    COMPUTE(cur)
    __syncthreads();        // drains vmcnt+lgkm, syncs all waves
    cur ^= 1;
  }
  COMPUTE(cur)

#pragma unroll
  for (int mi = 0; mi < 8; ++mi)
#pragma unroll
    for (int nj = 0; nj < 4; ++nj)
#pragma unroll
      for (int r = 0; r < 4; ++r) {
        int m = bm * 256 + wr * 128 + mi * 16 + fq * 4 + r;
        int n = bn * 256 + wc * 64 + nj * 16 + fr;
        C[(int64_t)m * NTOT + n] = f2bf(acc[mi][nj][r]);
      }
#undef STG
#undef COMPUTE
}

// ---------------------------------------------------------------------------
// Kernel 3: wave-per-gate LayerNorm + LSTM pointwise (r6-r10 verified)
// ---------------------------------------------------------------------------
__device__ __forceinline__ float2 block_meanvar(float s, float ss, float* sbuf,
                                                int lane, int wid) {
#pragma unroll
  for (int off = 32; off > 0; off >>= 1) {
    s  += __shfl_down(s, off);
    ss += __shfl_down(ss, off);
  }
  if (lane == 0) { sbuf[wid] = s; sbuf[4 + wid] = ss; }
  __syncthreads();
  if (threadIdx.x == 0) {
    float S  = sbuf[0] + sbuf[1] + sbuf[2] + sbuf[3];
    float SS = sbuf[4] + sbuf[5] + sbuf[6] + sbuf[7];
    float mean = S * (1.0f / 1024.0f);
    float var  = SS * (1.0f / 1024.0f) - mean * mean;
    var = fmaxf(var, 0.0f);
    float vf = (var < 1e-12f) ? 0.01f : 0.0f;
    sbuf[8] = mean;
    sbuf[9] = 1.0f / sqrtf(var + 1e-12f + vf);
  }
  __syncthreads();
  return make_float2(sbuf[8], sbuf[9]);
}

__device__ __forceinline__ float sigmoidf_(float x) {
  return 1.0f / (1.0f + expf(-x));
}

__global__ __launch_bounds__(256) void lstm_post2_kernel(
    const unsigned short* __restrict__ gates,
    const float* __restrict__ cx,
    const float* __restrict__ gamma,
    const float* __restrict__ beta,
    float* __restrict__ out) {
  __shared__ float act[4][1024];
  __shared__ float red[10];
  const int b = blockIdx.x;
  const int t = threadIdx.x;
  const int lane = t & 63, g = t >> 6;

  const unsigned short* grow = gates + (int64_t)b * 4096 + (g << 10);
  float v[4][4];
  float s = 0.f, ss = 0.f;
#pragma unroll
  for (int q = 0; q < 4; ++q) {
    u16x4 raw = *(const u16x4*)(grow + q * 256 + lane * 4);
#pragma unroll
    for (int j = 0; j < 4; ++j) {
      float f = bf2f(raw[j]);
      v[q][j] = f; s += f; ss += f * f;
    }
  }
#pragma unroll
  for (int off = 32; off > 0; off >>= 1) {
    s  += __shfl_xor(s, off);
    ss += __shfl_xor(ss, off);
  }
  float mean = s * (1.0f / 1024.0f);
  float var  = fmaxf(ss * (1.0f / 1024.0f) - mean * mean, 0.0f);
  float vf   = (var < 1e-12f) ? 0.01f : 0.0f;
  float rstd = 1.0f / sqrtf(var + 1e-12f + vf);

#pragma unroll
  for (int q = 0; q < 4; ++q) {
    const int idx = q * 256 + lane * 4;
    f32x4 gm = *(const f32x4*)(gamma + (g << 10) + idx);
    f32x4 bt = *(const f32x4*)(beta  + (g << 10) + idx);
    f32x4 aa;
#pragma unroll
    for (int j = 0; j < 4; ++j) {
      float n = (v[q][j] - mean) * rstd * gm[j] + bt[j];
      if (g == 1)      aa[j] = sigmoidf_(n + 1.0f);   // forget + FORGET_BIAS
      else if (g == 2) aa[j] = tanhf(n);              // cellgate
      else             aa[j] = sigmoidf_(n);          // in / out gates
    }
    *(f32x4*)(&act[g][idx]) = aa;
  }
  __syncthreads();

  const int h = t * 4;
  f32x4 ig  = *(const f32x4*)(&act[0][h]);
  f32x4 fg  = *(const f32x4*)(&act[1][h]);
  f32x4 cg  = *(const f32x4*)(&act[2][h]);
  f32x4 og  = *(const f32x4*)(&act[3][h]);
  f32x4 cxv = *(const f32x4*)(cx + ((int64_t)b << 10) + h);

  float cyr[4];
  float s2 = 0.f, ss2 = 0.f;
#pragma unroll
  for (int j = 0; j < 4; ++j) {
    cyr[j] = fg[j] * cxv[j] + ig[j] * cg[j];
    s2 += cyr[j]; ss2 += cyr[j] * cyr[j];
  }
  float2 mv = block_meanvar(s2, ss2, red, lane, g);
  f32x4 gm4 = *(const f32x4*)(gamma + 4096 + h);
  f32x4 bt4 = *(const f32x4*)(beta  + 4096 + h);

  f32x4 hy, cyn;
#pragma unroll
  for (int j = 0; j < 4; ++j) {
    float n = (cyr[j] - mv.x) * mv.y * gm4[j] + bt4[j];
    cyn[j] = n;
    hy[j]  = og[j] * tanhf(n);
  }

  const int64_t base = ((int64_t)b << 10) + h;
  *(f32x4*)(out + base)                    = hy;   // hy_dropped
  *(f32x4*)(out + (int64_t)4194304 + base) = hy;   // hy
  *(f32x4*)(out + (int64_t)8388608 + base) = cyn;  // cy
}

// ---------------------------------------------------------------------------
extern "C" void kernel_launch(void* const* d_in, const int* in_sizes, int n_in,
                              void* d_out, int out_size, void* d_ws, size_t ws_size,
                              hipStream_t stream) {
  (void)in_sizes; (void)n_in; (void)out_size; (void)ws_size;
  const float* x     = (const float*)d_in[0];
  const float* hx    = (const float*)d_in[1];
  const float* cx    = (const float*)d_in[2];
  const float* wih   = (const float*)d_in[3];
  const float* whh   = (const float*)d_in[4];
  const float* gamma = (const float*)d_in[5];
  const float* beta  = (const float*)d_in[6];
  float* out = (float*)d_out;

  unsigned short* Abf   = (unsigned short*)d_ws;            // 16MB
  unsigned short* Bbf   = Abf + (size_t)4096 * 2048;        // 16MB
  unsigned short* gates = Bbf + (size_t)4096 * 2048;        // 32MB

  concat2_kernel<<<8192, 256, 0, stream>>>(x, hx, wih, whh, Abf, Bbf);
  gemm256p_kernel<<<256, 512, 0, stream>>>(Abf, Bbf, gates);
  lstm_post2_kernel<<<4096, 256, 0, stream>>>(gates, cx, gamma, beta, out);
}